// Round 3
// baseline (258.614 us; speedup 1.0000x reference)
//
#include <hip/hip_runtime.h>

// BSQ forward: x (65536x512 f32) -> z (x16) -> sign bits -> decode (x512).
// Normalize is sign-invariant -> skipped; STE forward output == sign(z).
//
// NUMERICS: borderline z (~1e-7) exist; must match the np reference's f32
// sign decisions BITWISE. np.einsum (optimize=False) hits
// float_sum_of_products_contig_outstride0_two, compiled with numpy's
// BASELINE SIMD (not dispatched): x86_64 wheels = SSE/SSE2/SSE3:
//   vstep = 4 lanes, npyv_muladd = separate mul+add (NO FMA in baseline!)
//   main loop, chunks of 16: vaccum = a0*b0 + (a1*b1 + (a2*b2 + (a3*b3 + vaccum)))
//     (REVERSED subvector chain -- a3 hits the accumulator first)
//   npyv_sum_f32 (SSE3 hadd): (p0+p1) + (p2+p3)
//   then z + b_enc as a separate f32 add.
// We emulate with __fmul_rn/__fadd_rn (blocks FMA contraction).

constexpr int DIM  = 512;
constexpr int NC   = 16;
constexpr int TPB  = 64;     // tokens per block
constexpr int NTOK = 65536;

__device__ __forceinline__ float mul_rn(float a, float b) { return __fmul_rn(a, b); }
__device__ __forceinline__ float add_rn(float a, float b) { return __fadd_rn(a, b); }

__global__ __launch_bounds__(256, 2) void bsq_main(
    const float* __restrict__ x,
    const float* __restrict__ Wenc,   // (16, 512)
    const float* __restrict__ benc,   // (16,)
    const float* __restrict__ Wdec,   // (512, 16)
    const float* __restrict__ bdec,   // (512,)
    float* __restrict__ out)          // (65536, 512)
{
    // W: [col4 0..127][c 0..15] float4  -> read addr stride 64B over c: 2-way bank = free
    // x: per wave [col4 0..127][tok 0..3] float4 -> 4 distinct addrs, 16-lane bcast: conflict-free
    __shared__ float4 s_w4[2048];        // 32 KB
    __shared__ float4 s_x4[4][512];      // 32 KB (reused for codes after encode)

    const int tid  = threadIdx.x;
    const int lane = tid & 63;
    const int wv   = tid >> 6;           // wave 0..3, owns 16 tokens
    const int tsub = lane >> 4;          // token-in-round 0..3
    const int c    = lane & 15;          // channel
    const size_t tok0 = (size_t)blockIdx.x * TPB;

    // ---- stage W into LDS (col4-major) ----
    {
        const float4* wg = (const float4*)Wenc;
#pragma unroll
        for (int q = 0; q < 8; ++q) {
            int idx  = q * 256 + tid;    // 0..2047
            int row  = idx >> 7;         // c
            int col4 = idx & 127;
            s_w4[col4 * 16 + row] = wg[idx];
        }
    }
    __syncthreads();

    const float bc = benc[c];
    const float4* xg = (const float4*)(x + (tok0 + (size_t)wv * 16) * DIM);

    // prefetch round 0 (coalesced: consecutive lanes -> consecutive float4)
    float4 pf[8];
#pragma unroll
    for (int q = 0; q < 8; ++q) pf[q] = xg[q * 64 + lane];

    unsigned mycode = 0;   // lanes 0..15 end up holding token (wv*16+lane)'s code

    for (int r = 0; r < 4; ++r) {
        // write prefetched 4 tokens into this wave's private slab (token-interleaved)
#pragma unroll
        for (int q = 0; q < 8; ++q) {
            int idx  = q * 64 + lane;    // 0..511
            int trow = idx >> 7;         // token 0..3
            int col4 = idx & 127;
            s_x4[wv][col4 * 4 + trow] = pf[q];
        }
        // issue next round's global loads now; consumed next iteration
        if (r < 3) {
            const float4* nx = xg + (r + 1) * 512;
#pragma unroll
            for (int q = 0; q < 8; ++q) pf[q] = nx[q * 64 + lane];
        }
        // cross-lane LDS visibility within the wave (no __syncthreads needed:
        // wave-private slab, wave-lockstep, in-order DS pipe + explicit drain)
        asm volatile("s_waitcnt lgkmcnt(0)" ::: "memory");
        __builtin_amdgcn_wave_barrier();

        // ---- numpy SSE sum-of-products emulation ----
        float p0 = 0.f, p1 = 0.f, p2 = 0.f, p3 = 0.f;   // partial k = d mod 4
#pragma unroll 4
        for (int i = 0; i < 32; ++i) {                   // 16-element chunks
            float4 x0 = s_x4[wv][(4 * i + 0) * 4 + tsub];
            float4 x1 = s_x4[wv][(4 * i + 1) * 4 + tsub];
            float4 x2 = s_x4[wv][(4 * i + 2) * 4 + tsub];
            float4 x3 = s_x4[wv][(4 * i + 3) * 4 + tsub];
            float4 w0 = s_w4[(4 * i + 0) * 16 + c];
            float4 w1 = s_w4[(4 * i + 1) * 16 + c];
            float4 w2 = s_w4[(4 * i + 2) * 16 + c];
            float4 w3 = s_w4[(4 * i + 3) * 16 + c];
            float t;
            t  = add_rn(mul_rn(x3.x, w3.x), p0);
            t  = add_rn(mul_rn(x2.x, w2.x), t);
            t  = add_rn(mul_rn(x1.x, w1.x), t);
            p0 = add_rn(mul_rn(x0.x, w0.x), t);
            t  = add_rn(mul_rn(x3.y, w3.y), p1);
            t  = add_rn(mul_rn(x2.y, w2.y), t);
            t  = add_rn(mul_rn(x1.y, w1.y), t);
            p1 = add_rn(mul_rn(x0.y, w0.y), t);
            t  = add_rn(mul_rn(x3.z, w3.z), p2);
            t  = add_rn(mul_rn(x2.z, w2.z), t);
            t  = add_rn(mul_rn(x1.z, w1.z), t);
            p2 = add_rn(mul_rn(x0.z, w0.z), t);
            t  = add_rn(mul_rn(x3.w, w3.w), p3);
            t  = add_rn(mul_rn(x2.w, w2.w), t);
            t  = add_rn(mul_rn(x1.w, w1.w), t);
            p3 = add_rn(mul_rn(x0.w, w0.w), t);
        }
        // SSE3 hadd tree, then + b_enc as separate add
        float zs = add_rn(add_rn(p0, p1), add_rn(p2, p3));
        float z  = add_rn(zs, bc);

        unsigned long long m = __ballot(z >= 0.0f);      // bit (16*tsub + c)
        if ((lane >> 2) == r)                            // lane 4r+t keeps token r*4+t
            mycode = (unsigned)((m >> ((lane & 3) * 16)) & 0xFFFFull);
    }

    // park this wave's 16 codes in its (now dead) x slab
    if (lane < 16) ((unsigned*)&s_x4[wv][0])[lane] = mycode;
    __syncthreads();

    // ---- decode: thread owns output columns 2*tid, 2*tid+1 ----
    float wa[NC], wb[NC];
    {
        const float4* wrow = (const float4*)(Wdec + tid * 32);
#pragma unroll
        for (int p = 0; p < 4; ++p) {
            float4 v = wrow[p];
            wa[p * 4 + 0] = v.x; wa[p * 4 + 1] = v.y;
            wa[p * 4 + 2] = v.z; wa[p * 4 + 3] = v.w;
        }
#pragma unroll
        for (int p = 0; p < 4; ++p) {
            float4 v = wrow[4 + p];
            wb[p * 4 + 0] = v.x; wb[p * 4 + 1] = v.y;
            wb[p * 4 + 2] = v.z; wb[p * 4 + 3] = v.w;
        }
    }
    const float2 bdv = *(const float2*)(bdec + 2 * tid);
    float* op = out + tok0 * DIM + 2 * tid;

    // lane l holds code of block-token l
    int cv = (int)((const unsigned*)&s_x4[0][0])[(lane >> 4) * 2048 + (lane & 15)];
#pragma unroll 4
    for (int t2 = 0; t2 < TPB; ++t2) {
        unsigned code = (unsigned)__builtin_amdgcn_readlane(cv, t2);  // wave-uniform
        float o0 = bdv.x, o1 = bdv.y;
#pragma unroll
        for (int cc = 0; cc < NC; ++cc) {
            float s = ((code >> cc) & 1u) ? 1.0f : -1.0f;   // scalar cselect
            o0 = fmaf(wa[cc], s, o0);
            o1 = fmaf(wb[cc], s, o1);
        }
        *(float2*)(op + (size_t)t2 * DIM) = make_float2(o0, o1);      // coalesced
    }
}

extern "C" void kernel_launch(void* const* d_in, const int* in_sizes, int n_in,
                              void* d_out, int out_size, void* d_ws, size_t ws_size,
                              hipStream_t stream) {
    const float* x    = (const float*)d_in[0];
    const float* Wenc = (const float*)d_in[1];
    const float* benc = (const float*)d_in[2];
    const float* Wdec = (const float*)d_in[3];
    const float* bdec = (const float*)d_in[4];
    float* out = (float*)d_out;

    bsq_main<<<dim3(NTOK / TPB), dim3(256), 0, stream>>>(x, Wenc, benc, Wdec, bdec, out);
}